// Round 4
// baseline (460.632 us; speedup 1.0000x reference)
//
#include <hip/hip_runtime.h>
#include <hip/hip_bf16.h>

// JointNet: out[b,t,u,v] = sum_j tanh(e[b,t,j] + d[b,u,j]) * W_out[v,j] + b_out[v]
//   e = h_enc @ W_enc^T + b_enc   (1600 x 512)
//   d = h_dec @ W_dec^T           (400 x 512)
// Main GEMM: M=80000, N=1024, K=512 (bf16 MFMA).
// Round 4: (1) deeper counted-vmcnt schedule — A(Z) loads issued in P1,
// B(Wb) loads in P2, waits vmcnt(8)@P2-end / vmcnt(2)@P4-end placed AFTER
// the MFMA clusters: every Z load gets 3-4 phases (~1200cy) of latency
// cover, Wb (L2-hot) 2 phases. (2) bijective XCD-aware job remap so the 4
// n-blocks of each m-tile run on the same XCD (Z working set 2MB + Wb 1MB
// fits the 4MB XCD L2). Swizzle from round 3 retained.

typedef short bf16x8 __attribute__((ext_vector_type(8)));
typedef float fx4 __attribute__((ext_vector_type(4)));

static constexpr int KD = 512;   // J = D_enc = D_dec = K
static constexpr int V = 1024;

__device__ inline unsigned short f2bf(float f) {
    union { float f; unsigned u; } v; v.f = f;
    unsigned r = v.u + 0x7fffu + ((v.u >> 16) & 1u);
    return (unsigned short)(r >> 16);
}
__device__ inline float bf2f(unsigned short h) {
    union { float f; unsigned u; } v; v.u = ((unsigned)h) << 16; return v.f;
}
__device__ inline float fast_tanh(float x) {
    float p = __builtin_amdgcn_exp2f(x * 2.885390081777926f);
    return 1.0f - 2.0f * __builtin_amdgcn_rcpf(p + 1.0f);
}
__device__ inline void gld_lds16(const void* g, void* l) {
    __builtin_amdgcn_global_load_lds(
        (const __attribute__((address_space(1))) void*)g,
        (__attribute__((address_space(3))) void*)l, 16, 0, 0);
}

// ---------------- prep: fused e-GEMM / d-GEMM / W_out->bf16 ----------------
// blocks 0..199: e (25 m-tiles x 8 n-tiles); 200..255: d (7 x 8); 256..511: cvt.
// GEMM: 64x64 tile, BK=32, 2-phase bf16 split (hiA*hiW + hiA*loW).
__global__ __launch_bounds__(256) void prep(
    const float* __restrict__ h_enc, const float* __restrict__ W_enc,
    const float* __restrict__ b_enc, const float* __restrict__ h_dec,
    const float* __restrict__ W_dec, const float* __restrict__ W_out,
    float* __restrict__ e, float* __restrict__ dd, unsigned short* __restrict__ Wb) {
    const int bx = blockIdx.x;
    const int t = threadIdx.x;
    if (bx >= 256) {
        // W_out fp32 -> bf16 : 1024*512 = 524288 elems, 256 blocks * 256 thr * 8
        int i = ((bx - 256) * 256 + t) * 8;
        fx4 a = *(const fx4*)(W_out + i);
        fx4 b = *(const fx4*)(W_out + i + 4);
        unsigned short p[8];
        #pragma unroll
        for (int j = 0; j < 4; j++) { p[j] = f2bf(a[j]); p[j + 4] = f2bf(b[j]); }
        *(bf16x8*)(Wb + i) = *(bf16x8*)p;
        return;
    }
    const float* A; const float* W; const float* bias; float* out;
    int Mrows, mb, nb;
    if (bx < 200) { A = h_enc; W = W_enc; bias = b_enc; out = e;  Mrows = 1600; mb = bx >> 3; nb = bx & 7; }
    else { int b2 = bx - 200; A = h_dec; W = W_dec; bias = nullptr; out = dd; Mrows = 400; mb = b2 >> 3; nb = b2 & 7; }

    __shared__ unsigned short As[64 * 32];
    __shared__ unsigned short Ws[64 * 32];
    const int lane = t & 63, wid = t >> 6;
    const int m0 = mb * 64, n0 = nb * 64;
    const int wm = (wid & 1) * 32, wn = (wid >> 1) * 32;

    fx4 acc[2][2];
    const fx4 z4 = {0.f, 0.f, 0.f, 0.f};
    acc[0][0] = z4; acc[0][1] = z4; acc[1][0] = z4; acc[1][1] = z4;

    const int sr = t >> 2;             // staged row 0..63
    const int skc = (t & 3) * 8;       // k chunk start
    const int ar = (m0 + sr < Mrows) ? (m0 + sr) : (Mrows - 1);
    const float* Ap = A + (size_t)ar * KD + skc;
    const float* Wp = W + (size_t)(n0 + sr) * KD + skc;
    unsigned short* asl = &As[sr * 32 + skc];
    unsigned short* wsl = &Ws[sr * 32 + skc];

    for (int ph = 0; ph < 2; ph++) {
        const int wmode = (ph == 1);  // take lo(W) on phase 1
        for (int kb = 0; kb < 16; kb++) {
            const int k0 = kb * 32;
            fx4 a0 = *(const fx4*)(Ap + k0);
            fx4 a1 = *(const fx4*)(Ap + k0 + 4);
            fx4 w0 = *(const fx4*)(Wp + k0);
            fx4 w1 = *(const fx4*)(Wp + k0 + 4);
            unsigned short pa[8], pw[8];
            #pragma unroll
            for (int i = 0; i < 4; i++) {
                unsigned short h;
                pa[i] = f2bf(a0[i]); pa[i + 4] = f2bf(a1[i]);
                h = f2bf(w0[i]); pw[i]     = wmode ? f2bf(w0[i] - bf2f(h)) : h;
                h = f2bf(w1[i]); pw[i + 4] = wmode ? f2bf(w1[i] - bf2f(h)) : h;
            }
            *(bf16x8*)asl = *(bf16x8*)pa;
            *(bf16x8*)wsl = *(bf16x8*)pw;
            __syncthreads();
            bf16x8 af[2], wf[2];
            #pragma unroll
            for (int f = 0; f < 2; f++) {
                af[f] = *(const bf16x8*)&As[(wm + f * 16 + (lane & 15)) * 32 + (lane >> 4) * 8];
                wf[f] = *(const bf16x8*)&Ws[(wn + f * 16 + (lane & 15)) * 32 + (lane >> 4) * 8];
            }
            #pragma unroll
            for (int fm = 0; fm < 2; fm++)
                #pragma unroll
                for (int fn = 0; fn < 2; fn++)
                    acc[fm][fn] = __builtin_amdgcn_mfma_f32_16x16x32_bf16(
                        af[fm], wf[fn], acc[fm][fn], 0, 0, 0);
            __syncthreads();
        }
    }
    // epilogue: C/D layout col=lane&15, row=(lane>>4)*4+reg
    const int colb = n0 + wn + (lane & 15);
    const int rowb = m0 + wm + (lane >> 4) * 4;
    float bo[2];
    bo[0] = bias ? bias[colb] : 0.f;
    bo[1] = bias ? bias[colb + 16] : 0.f;
    #pragma unroll
    for (int fm = 0; fm < 2; fm++) {
        #pragma unroll
        for (int r = 0; r < 4; r++) {
            int row = rowb + fm * 16 + r;
            if (row < Mrows) {
                float* op = out + (size_t)row * KD;
                op[colb] = acc[fm][0][r] + bo[0];
                op[colb + 16] = acc[fm][1][r] + bo[1];
            }
        }
    }
}

// ---------------- Z = tanh(e + d) materialized in bf16 ---------------------
__global__ __launch_bounds__(256) void tanh_z(
    const float* __restrict__ e, const float* __restrict__ d,
    unsigned short* __restrict__ Z) {
    const int t = threadIdx.x;
    const int m = blockIdx.x * 4 + (t >> 6);
    const int kc = (t & 63) * 8;
    const int bt = m / 50;
    const int u = m - bt * 50;
    const int b = m / 10000;
    const float* ep = e + (size_t)bt * KD + kc;
    const float* dp = d + (size_t)(b * 50 + u) * KD + kc;
    fx4 e0 = *(const fx4*)ep, e1 = *(const fx4*)(ep + 4);
    fx4 d0 = *(const fx4*)dp, d1 = *(const fx4*)(dp + 4);
    unsigned short p[8];
    #pragma unroll
    for (int i = 0; i < 4; i++) {
        p[i] = f2bf(fast_tanh(e0[i] + d0[i]));
        p[i + 4] = f2bf(fast_tanh(e1[i] + d1[i]));
    }
    *(bf16x8*)(Z + (size_t)m * KD + kc) = *(bf16x8*)p;
}

// ---------------- main GEMM: out = Z @ W_out^T + b_out ---------------------
// 256x256 tile, 8 waves (2M x 4N), BK=64 as two 256x32 K-slice halves.
// Double-buffered LDS (128 KiB). 4 phases per K-tile.
// Issue order per thread per K-tile kt (targets buffer cb2 = (kt+1)&1):
//   P1: A0(kt+1) x2, A1(kt+1) x2     (Z rows - HBM/L3, needs long cover)
//   P2: B0(kt+1) x2, B1(kt+1) x2     (Wb rows - L2-hot, short cover OK)
// Waits (after MFMA cluster, before closing barrier):
//   P2-end: vmcnt(8)  -> ensures B1(kt) (4-phase cover) before P3 reads it;
//                        leaves the 8 loads of tile kt+1 in flight.
//   P4-end: vmcnt(2)  -> ensures A0,A1,B0(kt+1) (3/3/2-phase cover) before
//                        next tile's P1/P3 reads; leaves B1(kt+1) x2.
// Tail kt=7: no issues; P2-end vmcnt(0) drains B1(7).
// FIFO bookkeeping verified incl. prologue (issue A0,A1,B0,B1 of tile 0,
// then vmcnt(2): A0,A1,B0(0) resident before first reads).
// T2 swizzle retained: LDS slot s holds logical chunk s ^ ((row>>1)&3),
// staged via pre-swizzled global source, read via swizzled slot.
__global__ __launch_bounds__(512, 2) void gemm_out_k8(
    const unsigned short* __restrict__ Z, const unsigned short* __restrict__ Wb,
    const float* __restrict__ b_out, float* __restrict__ out) {
    __shared__ unsigned short As[2][2][256 * 32];   // [dbuf][ks-half][row][32]
    __shared__ unsigned short Bs[2][2][256 * 32];
    const int t = threadIdx.x;
    const int lane = t & 63, wid = t >> 6;
    const int bid = blockIdx.x;
    // Bijective XCD remap (nwg=1252, q=156, r=4): XCD x = bid&7 processes
    // contiguous m-major jobs -> the 4 n-blocks of each m-tile share an XCD;
    // live Z set = 8 m-tiles * 256KB = 2MB + Wb 1MB < 4MB XCD L2.
    const int xcd = bid & 7, ix = bid >> 3;
    const int j = (xcd < 4) ? xcd * 157 + ix : 628 + (xcd - 4) * 156 + ix;
    const int n0 = (j & 3) * 256;
    const int m0 = (j >> 2) * 256;
    const int wm = (wid >> 2) * 128;   // 2 wave-rows
    const int wn = (wid & 3) * 64;     // 4 wave-cols

    fx4 acc[8][4];
    const fx4 z4 = {0.f, 0.f, 0.f, 0.f};
    #pragma unroll
    for (int i = 0; i < 8; i++)
        #pragma unroll
        for (int jj = 0; jj < 4; jj++) acc[i][jj] = z4;

    // staging: issue q covers rows (wid*2+q)*16 + (lane>>2); LDS slot lane&3
    // holds logical chunk (lane&3) ^ ((lane>>3)&3)  [= slot ^ ((row>>1)&3)].
    size_t gA[2], gB[2];
    int lb[2];
    {
        const int kcs = ((lane & 3) ^ ((lane >> 3) & 3)) * 8;  // swizzled source chunk
        #pragma unroll
        for (int q = 0; q < 2; q++) {
            int rl = (wid * 2 + q) * 16 + (lane >> 2);
            int ra = m0 + rl; if (ra > 79999) ra = 79999;   // tail m-tile clamp
            gA[q] = (size_t)ra * KD + kcs;
            gB[q] = (size_t)(n0 + rl) * KD + kcs;
            lb[q] = (wid * 2 + q) * 512;   // wave-uniform LDS base (shorts)
        }
    }

    // frag read offsets (shorts): row*32 + swizzled-slot*8; frag step 16 rows = 512
    const int xsl = ((lane >> 4) ^ (((lane & 15) >> 1) & 3)) * 8;
    const int offA = (wm + (lane & 15)) * 32 + xsl;
    const int offB = (wn + (lane & 15)) * 32 + xsl;

    // prologue: stage K-tile 0 in queue order A0,A1,B0,B1; wait through B0.
    gld_lds16(Z + gA[0], &As[0][0][lb[0]]);
    gld_lds16(Z + gA[1], &As[0][0][lb[1]]);
    gld_lds16(Z + gA[0] + 32, &As[0][1][lb[0]]);
    gld_lds16(Z + gA[1] + 32, &As[0][1][lb[1]]);
    gld_lds16(Wb + gB[0], &Bs[0][0][lb[0]]);
    gld_lds16(Wb + gB[1], &Bs[0][0][lb[1]]);
    gld_lds16(Wb + gB[0] + 32, &Bs[0][1][lb[0]]);
    gld_lds16(Wb + gB[1] + 32, &Bs[0][1][lb[1]]);
    asm volatile("s_waitcnt vmcnt(2)" ::: "memory");   // A0,A1,B0(0) resident
    __builtin_amdgcn_s_barrier();

    #pragma unroll 2
    for (int kt = 0; kt < 8; kt++) {
        const int cb = kt & 1, cb2 = cb ^ 1;
        const size_t ko = (size_t)(kt + 1) * 64;
        const bool pf = (kt < 7);
        bf16x8 afA[4], afB[4], bfA[4];

        // ---- P1: ks0, m0-3 | issue A0(kt+1), A1(kt+1) ----
        #pragma unroll
        for (int i = 0; i < 4; i++) afA[i] = *(const bf16x8*)&As[cb][0][offA + i * 512];
        #pragma unroll
        for (int i = 0; i < 4; i++) bfA[i] = *(const bf16x8*)&Bs[cb][0][offB + i * 512];
        if (pf) {
            gld_lds16(Z + gA[0] + ko, &As[cb2][0][lb[0]]);
            gld_lds16(Z + gA[1] + ko, &As[cb2][0][lb[1]]);
            gld_lds16(Z + gA[0] + ko + 32, &As[cb2][1][lb[0]]);
            gld_lds16(Z + gA[1] + ko + 32, &As[cb2][1][lb[1]]);
        }
        __builtin_amdgcn_s_barrier();
        asm volatile("s_waitcnt lgkmcnt(0)" ::: "memory");
        __builtin_amdgcn_sched_barrier(0);
        __builtin_amdgcn_s_setprio(1);
        #pragma unroll
        for (int m = 0; m < 4; m++)
            #pragma unroll
            for (int n = 0; n < 4; n++)
                acc[m][n] = __builtin_amdgcn_mfma_f32_16x16x32_bf16(afA[m], bfA[n], acc[m][n], 0, 0, 0);
        __builtin_amdgcn_s_setprio(0);
        __builtin_amdgcn_s_barrier();

        // ---- P2: ks0, m4-7 | issue B0(kt+1), B1(kt+1); vmcnt(8) at end ----
        #pragma unroll
        for (int i = 0; i < 4; i++) afB[i] = *(const bf16x8*)&As[cb][0][offA + (4 + i) * 512];
        if (pf) {
            gld_lds16(Wb + gB[0] + ko, &Bs[cb2][0][lb[0]]);
            gld_lds16(Wb + gB[1] + ko, &Bs[cb2][0][lb[1]]);
            gld_lds16(Wb + gB[0] + ko + 32, &Bs[cb2][1][lb[0]]);
            gld_lds16(Wb + gB[1] + ko + 32, &Bs[cb2][1][lb[1]]);
        }
        __builtin_amdgcn_s_barrier();
        asm volatile("s_waitcnt lgkmcnt(0)" ::: "memory");
        __builtin_amdgcn_sched_barrier(0);
        __builtin_amdgcn_s_setprio(1);
        #pragma unroll
        for (int m = 0; m < 4; m++)
            #pragma unroll
            for (int n = 0; n < 4; n++)
                acc[4 + m][n] = __builtin_amdgcn_mfma_f32_16x16x32_bf16(afB[m], bfA[n], acc[4 + m][n], 0, 0, 0);
        __builtin_amdgcn_s_setprio(0);
        if (pf) {
            asm volatile("s_waitcnt vmcnt(8)" ::: "memory");   // B1(kt) resident for P3
        } else {
            asm volatile("s_waitcnt vmcnt(0)" ::: "memory");   // drain B1(7)
        }
        __builtin_amdgcn_s_barrier();

        // ---- P3: ks1, m0-3 ----
        #pragma unroll
        for (int i = 0; i < 4; i++) afA[i] = *(const bf16x8*)&As[cb][1][offA + i * 512];
        #pragma unroll
        for (int i = 0; i < 4; i++) bfA[i] = *(const bf16x8*)&Bs[cb][1][offB + i * 512];
        __builtin_amdgcn_s_barrier();
        asm volatile("s_waitcnt lgkmcnt(0)" ::: "memory");
        __builtin_amdgcn_sched_barrier(0);
        __builtin_amdgcn_s_setprio(1);
        #pragma unroll
        for (int m = 0; m < 4; m++)
            #pragma unroll
            for (int n = 0; n < 4; n++)
                acc[m][n] = __builtin_amdgcn_mfma_f32_16x16x32_bf16(afA[m], bfA[n], acc[m][n], 0, 0, 0);
        __builtin_amdgcn_s_setprio(0);
        __builtin_amdgcn_s_barrier();

        // ---- P4: ks1, m4-7 | vmcnt(2) at end ----
        #pragma unroll
        for (int i = 0; i < 4; i++) afB[i] = *(const bf16x8*)&As[cb][1][offA + (4 + i) * 512];
        __builtin_amdgcn_s_barrier();
        asm volatile("s_waitcnt lgkmcnt(0)" ::: "memory");
        __builtin_amdgcn_sched_barrier(0);
        __builtin_amdgcn_s_setprio(1);
        #pragma unroll
        for (int m = 0; m < 4; m++)
            #pragma unroll
            for (int n = 0; n < 4; n++)
                acc[4 + m][n] = __builtin_amdgcn_mfma_f32_16x16x32_bf16(afB[m], bfA[n], acc[4 + m][n], 0, 0, 0);
        __builtin_amdgcn_s_setprio(0);
        if (pf) {
            asm volatile("s_waitcnt vmcnt(2)" ::: "memory");   // A0,A1,B0(kt+1) resident
        }
        __builtin_amdgcn_s_barrier();
    }

    // epilogue: col=lane&15, row=(lane>>4)*4+reg
    const int colb = n0 + wn + (lane & 15);
    const int rowb = m0 + wm + (lane >> 4) * 4;
    float bo[4];
    #pragma unroll
    for (int fn = 0; fn < 4; fn++) bo[fn] = b_out[colb + fn * 16];
    #pragma unroll
    for (int fm = 0; fm < 8; fm++) {
        #pragma unroll
        for (int r = 0; r < 4; r++) {
            const int row = rowb + fm * 16 + r;
            if (row < 80000) {
                float* op = out + (size_t)row * V;
                #pragma unroll
                for (int fn = 0; fn < 4; fn++)
                    op[colb + fn * 16] = acc[fm][fn][r] + bo[fn];
            }
        }
    }
}

extern "C" void kernel_launch(void* const* d_in, const int* in_sizes, int n_in,
                              void* d_out, int out_size, void* d_ws, size_t ws_size,
                              hipStream_t stream) {
    const float* h_enc = (const float*)d_in[0];  // (8,200,1,512) = 1600x512
    const float* h_dec = (const float*)d_in[1];  // (8,1,50,512)  = 400x512
    const float* W_enc = (const float*)d_in[2];  // (512,512)
    const float* b_enc = (const float*)d_in[3];  // (512)
    const float* W_dec = (const float*)d_in[4];  // (512,512)
    const float* W_out = (const float*)d_in[5];  // (1024,512)
    const float* b_out = (const float*)d_in[6];  // (1024)
    float* out = (float*)d_out;                  // (8,200,50,1024)

    // workspace layout (~87 MB total)
    float* e = (float*)d_ws;                               // 1600*512 f32
    float* dd = e + 1600 * KD;                             // 400*512 f32
    unsigned short* Wb = (unsigned short*)(dd + 400 * KD); // 1024*512 bf16
    unsigned short* Zb = Wb + (size_t)V * KD;              // 80000*512 bf16

    prep<<<512, 256, 0, stream>>>(h_enc, W_enc, b_enc, h_dec, W_dec, W_out, e, dd, Wb);
    tanh_z<<<20000, 256, 0, stream>>>(e, dd, Zb);
    gemm_out_k8<<<313 * 4, 512, 0, stream>>>(Zb, Wb, b_out, out);
}

// Round 5
// 453.014 us; speedup vs baseline: 1.0168x; 1.0168x over previous
//
#include <hip/hip_runtime.h>
#include <hip/hip_bf16.h>

// JointNet: out[b,t,u,v] = sum_j tanh(e[b,t,j] + d[b,u,j]) * W_out[v,j] + b_out[v]
//   e = h_enc @ W_enc^T + b_enc   (1600 x 512)
//   d = h_dec @ W_dec^T           (400 x 512)
// Main GEMM: M=80000, N=1024, K=512 (bf16 MFMA).
// Round 5: sync-count reduction. The 4-phase schedule had 8 block-wide
// barriers per K-tile (64 total) -> lockstep jitter paid at every rendezvous
// (R3/R4 showed wait-depth & L2-locality tweaks neutral). New structure:
// BK=32 K-steps with a 4-deep LDS ring (4 x 32KB = 128KB, same footprint),
// ONE barrier per step (16 total), staging issued 3 steps ahead so the
// per-step vmcnt(8) drains loads issued ~2.5 steps (~1000cy) earlier --
// satisfied in steady state. Swizzle retained; R1 block mapping restored.

typedef short bf16x8 __attribute__((ext_vector_type(8)));
typedef float fx4 __attribute__((ext_vector_type(4)));

static constexpr int KD = 512;   // J = D_enc = D_dec = K
static constexpr int V = 1024;

__device__ inline unsigned short f2bf(float f) {
    union { float f; unsigned u; } v; v.f = f;
    unsigned r = v.u + 0x7fffu + ((v.u >> 16) & 1u);
    return (unsigned short)(r >> 16);
}
__device__ inline float bf2f(unsigned short h) {
    union { float f; unsigned u; } v; v.u = ((unsigned)h) << 16; return v.f;
}
__device__ inline float fast_tanh(float x) {
    float p = __builtin_amdgcn_exp2f(x * 2.885390081777926f);
    return 1.0f - 2.0f * __builtin_amdgcn_rcpf(p + 1.0f);
}
__device__ inline void gld_lds16(const void* g, void* l) {
    __builtin_amdgcn_global_load_lds(
        (const __attribute__((address_space(1))) void*)g,
        (__attribute__((address_space(3))) void*)l, 16, 0, 0);
}

// ---------------- prep: fused e-GEMM / d-GEMM / W_out->bf16 ----------------
// blocks 0..199: e (25 m-tiles x 8 n-tiles); 200..255: d (7 x 8); 256..511: cvt.
// GEMM: 64x64 tile, BK=32, 2-phase bf16 split (hiA*hiW + hiA*loW).
__global__ __launch_bounds__(256) void prep(
    const float* __restrict__ h_enc, const float* __restrict__ W_enc,
    const float* __restrict__ b_enc, const float* __restrict__ h_dec,
    const float* __restrict__ W_dec, const float* __restrict__ W_out,
    float* __restrict__ e, float* __restrict__ dd, unsigned short* __restrict__ Wb) {
    const int bx = blockIdx.x;
    const int t = threadIdx.x;
    if (bx >= 256) {
        // W_out fp32 -> bf16 : 1024*512 = 524288 elems, 256 blocks * 256 thr * 8
        int i = ((bx - 256) * 256 + t) * 8;
        fx4 a = *(const fx4*)(W_out + i);
        fx4 b = *(const fx4*)(W_out + i + 4);
        unsigned short p[8];
        #pragma unroll
        for (int j = 0; j < 4; j++) { p[j] = f2bf(a[j]); p[j + 4] = f2bf(b[j]); }
        *(bf16x8*)(Wb + i) = *(bf16x8*)p;
        return;
    }
    const float* A; const float* W; const float* bias; float* out;
    int Mrows, mb, nb;
    if (bx < 200) { A = h_enc; W = W_enc; bias = b_enc; out = e;  Mrows = 1600; mb = bx >> 3; nb = bx & 7; }
    else { int b2 = bx - 200; A = h_dec; W = W_dec; bias = nullptr; out = dd; Mrows = 400; mb = b2 >> 3; nb = b2 & 7; }

    __shared__ unsigned short As[64 * 32];
    __shared__ unsigned short Ws[64 * 32];
    const int lane = t & 63, wid = t >> 6;
    const int m0 = mb * 64, n0 = nb * 64;
    const int wm = (wid & 1) * 32, wn = (wid >> 1) * 32;

    fx4 acc[2][2];
    const fx4 z4 = {0.f, 0.f, 0.f, 0.f};
    acc[0][0] = z4; acc[0][1] = z4; acc[1][0] = z4; acc[1][1] = z4;

    const int sr = t >> 2;             // staged row 0..63
    const int skc = (t & 3) * 8;       // k chunk start
    const int ar = (m0 + sr < Mrows) ? (m0 + sr) : (Mrows - 1);
    const float* Ap = A + (size_t)ar * KD + skc;
    const float* Wp = W + (size_t)(n0 + sr) * KD + skc;
    unsigned short* asl = &As[sr * 32 + skc];
    unsigned short* wsl = &Ws[sr * 32 + skc];

    for (int ph = 0; ph < 2; ph++) {
        const int wmode = (ph == 1);  // take lo(W) on phase 1
        for (int kb = 0; kb < 16; kb++) {
            const int k0 = kb * 32;
            fx4 a0 = *(const fx4*)(Ap + k0);
            fx4 a1 = *(const fx4*)(Ap + k0 + 4);
            fx4 w0 = *(const fx4*)(Wp + k0);
            fx4 w1 = *(const fx4*)(Wp + k0 + 4);
            unsigned short pa[8], pw[8];
            #pragma unroll
            for (int i = 0; i < 4; i++) {
                unsigned short h;
                pa[i] = f2bf(a0[i]); pa[i + 4] = f2bf(a1[i]);
                h = f2bf(w0[i]); pw[i]     = wmode ? f2bf(w0[i] - bf2f(h)) : h;
                h = f2bf(w1[i]); pw[i + 4] = wmode ? f2bf(w1[i] - bf2f(h)) : h;
            }
            *(bf16x8*)asl = *(bf16x8*)pa;
            *(bf16x8*)wsl = *(bf16x8*)pw;
            __syncthreads();
            bf16x8 af[2], wf[2];
            #pragma unroll
            for (int f = 0; f < 2; f++) {
                af[f] = *(const bf16x8*)&As[(wm + f * 16 + (lane & 15)) * 32 + (lane >> 4) * 8];
                wf[f] = *(const bf16x8*)&Ws[(wn + f * 16 + (lane & 15)) * 32 + (lane >> 4) * 8];
            }
            #pragma unroll
            for (int fm = 0; fm < 2; fm++)
                #pragma unroll
                for (int fn = 0; fn < 2; fn++)
                    acc[fm][fn] = __builtin_amdgcn_mfma_f32_16x16x32_bf16(
                        af[fm], wf[fn], acc[fm][fn], 0, 0, 0);
            __syncthreads();
        }
    }
    // epilogue: C/D layout col=lane&15, row=(lane>>4)*4+reg
    const int colb = n0 + wn + (lane & 15);
    const int rowb = m0 + wm + (lane >> 4) * 4;
    float bo[2];
    bo[0] = bias ? bias[colb] : 0.f;
    bo[1] = bias ? bias[colb + 16] : 0.f;
    #pragma unroll
    for (int fm = 0; fm < 2; fm++) {
        #pragma unroll
        for (int r = 0; r < 4; r++) {
            int row = rowb + fm * 16 + r;
            if (row < Mrows) {
                float* op = out + (size_t)row * KD;
                op[colb] = acc[fm][0][r] + bo[0];
                op[colb + 16] = acc[fm][1][r] + bo[1];
            }
        }
    }
}

// ---------------- Z = tanh(e + d) materialized in bf16 ---------------------
__global__ __launch_bounds__(256) void tanh_z(
    const float* __restrict__ e, const float* __restrict__ d,
    unsigned short* __restrict__ Z) {
    const int t = threadIdx.x;
    const int m = blockIdx.x * 4 + (t >> 6);
    const int kc = (t & 63) * 8;
    const int bt = m / 50;
    const int u = m - bt * 50;
    const int b = m / 10000;
    const float* ep = e + (size_t)bt * KD + kc;
    const float* dp = d + (size_t)(b * 50 + u) * KD + kc;
    fx4 e0 = *(const fx4*)ep, e1 = *(const fx4*)(ep + 4);
    fx4 d0 = *(const fx4*)dp, d1 = *(const fx4*)(dp + 4);
    unsigned short p[8];
    #pragma unroll
    for (int i = 0; i < 4; i++) {
        p[i] = f2bf(fast_tanh(e0[i] + d0[i]));
        p[i + 4] = f2bf(fast_tanh(e1[i] + d1[i]));
    }
    *(bf16x8*)(Z + (size_t)m * KD + kc) = *(bf16x8*)p;
}

// ---------------- main GEMM: out = Z @ W_out^T + b_out ---------------------
// 256x256 tile, 8 waves (2M x 4N, wave tile 128x64), BK=32, 16 K-steps.
// 4-deep LDS ring: As/Bs[4][256*32] shorts = 128 KiB total.
// Per step kt: issue stage(kt+3) into ring slot (kt+3)&3 | ds_read 12 frags
// of slot kt&3 | lgkmcnt(0) | 32 MFMA (setprio) | vmcnt(8) | ONE barrier.
// FIFO (4 glds/thread/step): queue at step end = [kt+1(4), kt+2(4), kt+3(4)];
// vmcnt(8) drains kt+1 (issued 2.5 steps earlier, ~1000cy cover >= HBM).
// Ring overwrite safety: slot (kt+3)&3 == (kt-1)&3; its readers finished
// before barrier(kt-1), which precedes this step's stage issues.
// Tail: kt=13 -> vmcnt(4), kt=14 -> vmcnt(0), kt=15 no wait.
// T2 swizzle retained: LDS slot s holds logical chunk s ^ ((row>>1)&3),
// staged via pre-swizzled global source, read via swizzled slot.
__global__ __launch_bounds__(512, 2) void gemm_out_r(
    const unsigned short* __restrict__ Z, const unsigned short* __restrict__ Wb,
    const float* __restrict__ b_out, float* __restrict__ out) {
    __shared__ unsigned short As[4][256 * 32];   // [ring][row][32]
    __shared__ unsigned short Bs[4][256 * 32];
    const int t = threadIdx.x;
    const int lane = t & 63, wid = t >> 6;
    const int bid = blockIdx.x;
    const int n0 = (bid & 3) * 256;    // R1 mapping (best measured)
    const int m0 = (bid >> 2) * 256;
    const int wm = (wid >> 2) * 128;   // 2 wave-rows
    const int wn = (wid & 3) * 64;     // 4 wave-cols

    fx4 acc[8][4];
    const fx4 z4 = {0.f, 0.f, 0.f, 0.f};
    #pragma unroll
    for (int i = 0; i < 8; i++)
        #pragma unroll
        for (int j = 0; j < 4; j++) acc[i][j] = z4;

    // staging: issue q covers rows q*128 + wid*16 + (lane>>2), chunk slot
    // lane&3 holds logical chunk (lane&3)^((lane>>3)&3)  [= slot^((row>>1)&3)].
    size_t gA[2], gB[2];
    int lb[2];
    {
        const int kcs = ((lane & 3) ^ ((lane >> 3) & 3)) * 8;  // swizzled source chunk
        #pragma unroll
        for (int q = 0; q < 2; q++) {
            int rl = q * 128 + wid * 16 + (lane >> 2);
            int ra = m0 + rl; if (ra > 79999) ra = 79999;   // tail m-tile clamp
            gA[q] = (size_t)ra * KD + kcs;
            gB[q] = (size_t)(n0 + rl) * KD + kcs;
            lb[q] = q * 4096 + wid * 512;   // wave-uniform LDS base (shorts)
        }
    }

    // frag read offsets (shorts): row*32 + swizzled-slot*8; frag step 16 rows = 512
    const int xsl = ((lane >> 4) ^ (((lane & 15) >> 1) & 3)) * 8;
    const int offA = (wm + (lane & 15)) * 32 + xsl;
    const int offB = (wn + (lane & 15)) * 32 + xsl;

    // prologue: stage K-steps 0,1,2 into ring slots 0,1,2 (12 glds/thread).
    #pragma unroll
    for (int p = 0; p < 3; p++) {
        const size_t ko = (size_t)p * 32;
        gld_lds16(Z + gA[0] + ko, &As[p][lb[0]]);
        gld_lds16(Z + gA[1] + ko, &As[p][lb[1]]);
        gld_lds16(Wb + gB[0] + ko, &Bs[p][lb[0]]);
        gld_lds16(Wb + gB[1] + ko, &Bs[p][lb[1]]);
    }
    asm volatile("s_waitcnt vmcnt(8)" ::: "memory");   // step-0 tile resident
    __builtin_amdgcn_s_barrier();

    #pragma unroll 4
    for (int kt = 0; kt < 16; kt++) {
        const int r = kt & 3;
        const int s = (kt + 3) & 3;
        const size_t ko = (size_t)(kt + 3) * 32;

        // issue stage(kt+3) first (fire-and-forget, earliest HBM issue)
        if (kt <= 12) {
            gld_lds16(Z + gA[0] + ko, &As[s][lb[0]]);
            gld_lds16(Z + gA[1] + ko, &As[s][lb[1]]);
            gld_lds16(Wb + gB[0] + ko, &Bs[s][lb[0]]);
            gld_lds16(Wb + gB[1] + ko, &Bs[s][lb[1]]);
        }

        // ds_read this step's fragments
        bf16x8 af[8], bf[4];
        #pragma unroll
        for (int f = 0; f < 8; f++) af[f] = *(const bf16x8*)&As[r][offA + f * 512];
        #pragma unroll
        for (int f = 0; f < 4; f++) bf[f] = *(const bf16x8*)&Bs[r][offB + f * 512];

        asm volatile("s_waitcnt lgkmcnt(0)" ::: "memory");
        __builtin_amdgcn_sched_barrier(0);
        __builtin_amdgcn_s_setprio(1);
        #pragma unroll
        for (int m = 0; m < 8; m++)
            #pragma unroll
            for (int n = 0; n < 4; n++)
                acc[m][n] = __builtin_amdgcn_mfma_f32_16x16x32_bf16(af[m], bf[n], acc[m][n], 0, 0, 0);
        __builtin_amdgcn_s_setprio(0);

        // counted drain: ensure step kt+1's tile resident before next step
        if (kt <= 12) {
            asm volatile("s_waitcnt vmcnt(8)" ::: "memory");
        } else if (kt == 13) {
            asm volatile("s_waitcnt vmcnt(4)" ::: "memory");
        } else if (kt == 14) {
            asm volatile("s_waitcnt vmcnt(0)" ::: "memory");
        }
        __builtin_amdgcn_s_barrier();
    }

    // epilogue: col=lane&15, row=(lane>>4)*4+reg
    const int colb = n0 + wn + (lane & 15);
    const int rowb = m0 + wm + (lane >> 4) * 4;
    float bo[4];
    #pragma unroll
    for (int fn = 0; fn < 4; fn++) bo[fn] = b_out[colb + fn * 16];
    #pragma unroll
    for (int fm = 0; fm < 8; fm++) {
        #pragma unroll
        for (int r = 0; r < 4; r++) {
            const int row = rowb + fm * 16 + r;
            if (row < 80000) {
                float* op = out + (size_t)row * V;
                #pragma unroll
                for (int fn = 0; fn < 4; fn++)
                    op[colb + fn * 16] = acc[fm][fn][r] + bo[fn];
            }
        }
    }
}

extern "C" void kernel_launch(void* const* d_in, const int* in_sizes, int n_in,
                              void* d_out, int out_size, void* d_ws, size_t ws_size,
                              hipStream_t stream) {
    const float* h_enc = (const float*)d_in[0];  // (8,200,1,512) = 1600x512
    const float* h_dec = (const float*)d_in[1];  // (8,1,50,512)  = 400x512
    const float* W_enc = (const float*)d_in[2];  // (512,512)
    const float* b_enc = (const float*)d_in[3];  // (512)
    const float* W_dec = (const float*)d_in[4];  // (512,512)
    const float* W_out = (const float*)d_in[5];  // (1024,512)
    const float* b_out = (const float*)d_in[6];  // (1024)
    float* out = (float*)d_out;                  // (8,200,50,1024)

    // workspace layout (~87 MB total)
    float* e = (float*)d_ws;                               // 1600*512 f32
    float* dd = e + 1600 * KD;                             // 400*512 f32
    unsigned short* Wb = (unsigned short*)(dd + 400 * KD); // 1024*512 bf16
    unsigned short* Zb = Wb + (size_t)V * KD;              // 80000*512 bf16

    prep<<<512, 256, 0, stream>>>(h_enc, W_enc, b_enc, h_dec, W_dec, W_out, e, dd, Wb);
    tanh_z<<<20000, 256, 0, stream>>>(e, dd, Zb);
    gemm_out_r<<<313 * 4, 512, 0, stream>>>(Zb, Wb, b_out, out);
}